// Round 9
// baseline (471.434 us; speedup 1.0000x reference)
//
#include <hip/hip_runtime.h>

#define B_ 256
#define T_ 512
#define I_ 256
#define H_ 256
#define CHUNK 64

typedef float    f32x4 __attribute__((ext_vector_type(4)));
typedef _Float16 f16x2 __attribute__((ext_vector_type(2)));
typedef _Float16 f16x8 __attribute__((ext_vector_type(8)));

static __device__ __forceinline__ f16x8 cvt8(f32x4 a, f32x4 b) {
  return f16x8{(_Float16)a[0], (_Float16)a[1], (_Float16)a[2], (_Float16)a[3],
               (_Float16)b[0], (_Float16)b[1], (_Float16)b[2], (_Float16)b[3]};
}

// ---------------- fused RNN v8: 4 waves, 64 output cols per wave ----------------
// One block per batch row, 256 threads (4 waves, 1/SIMD, __launch_bounds__(256,1)
// -> full 512-VGPR budget; weight frags W_h + W_x = 256 VGPR held stationary).
// Transposed MFMA (A = broadcast h / x-rows, B = stationary weight frags, D col =
// output index): every D row = y, epilogue reads reg 0 only.
// Phase structure per 64-step chunk keeps ALL global ops off the per-step barrier
// path; phase 2 touches only LDS. vs v7: waves 8->4 halves the per-step LDS
// h-read instruction count (the measured bottleneck) and barrier width, at the
// cost of 2x MFMA issue per wave (pipe was idle anyway).
__global__ __launch_bounds__(256, 1) void rnn_fused(const float* __restrict__ x,
                                                    const float* __restrict__ wxf,
                                                    const float* __restrict__ whf,
                                                    const float* __restrict__ bias_g,
                                                    float* __restrict__ io) {
  __shared__ __align__(16) float    xps[CHUNK][H_];   // 64KB: xp + bias, current chunk
  __shared__ __align__(16) float    outs[CHUNK][H_];  // 64KB: staged outputs
  __shared__ __align__(16) _Float16 hb[2][H_];        // 1KB: double-buffered h (f16)

  const int tid = threadIdx.x;
  const int l   = tid & 63;
  const int w   = tid >> 6;
  const int lr  = l & 15;
  const int g   = l >> 4;
  const int h0  = w * 64;                             // wave owns cols [h0, h0+64)
  const size_t base = (size_t)blockIdx.x * (size_t)(T_ * H_);

  // Stationary B-fragments: frag[ct*8+kc] -> lane holds M[h0+ct*16+lr][kc*32+g*8 ..+8)
  f16x8 whF[32];   // W_h: 128 VGPR
  f16x8 wxF[32];   // W_x: 128 VGPR
#pragma unroll
  for (int ct = 0; ct < 4; ++ct) {
#pragma unroll
    for (int kc = 0; kc < 8; ++kc) {
      const float* ph = whf + (size_t)(h0 + ct * 16 + lr) * H_ + kc * 32 + g * 8;
      whF[ct * 8 + kc] = cvt8(*(const f32x4*)ph, *(const f32x4*)(ph + 4));
      const float* px = wxf + (size_t)(h0 + ct * 16 + lr) * I_ + kc * 32 + g * 8;
      wxF[ct * 8 + kc] = cvt8(*(const f32x4*)px, *(const f32x4*)(px + 4));
    }
  }
  float bias[4];
#pragma unroll
  for (int ct = 0; ct < 4; ++ct) bias[ct] = bias_g[h0 + ct * 16 + lr];

  if (tid < 128) ((f16x2*)hb[0])[tid] = f16x2{(_Float16)0.f, (_Float16)0.f};

  int cur = 0;
  for (int t0 = 0; t0 < T_; t0 += CHUNK) {
    // ---- phase 1: xp chunk straight from global x; D rows = t-steps ----
#pragma unroll 1
    for (int tt = 0; tt < CHUNK / 16; ++tt) {
      f32x4 accE[4] = {}, accO[4] = {};
      const float* xrow = x + base + (size_t)(t0 + tt * 16 + lr) * I_;
#pragma unroll
      for (int kc = 0; kc < 8; kc += 2) {
        const f32x4* p0 = (const f32x4*)(xrow + kc * 32 + g * 8);
        f16x8 a0 = cvt8(p0[0], p0[1]);
        const f32x4* p1 = (const f32x4*)(xrow + (kc + 1) * 32 + g * 8);
        f16x8 a1 = cvt8(p1[0], p1[1]);
#pragma unroll
        for (int ct = 0; ct < 4; ++ct) {
          accE[ct] = __builtin_amdgcn_mfma_f32_16x16x32_f16(a0, wxF[ct * 8 + kc],     accE[ct], 0, 0, 0);
          accO[ct] = __builtin_amdgcn_mfma_f32_16x16x32_f16(a1, wxF[ct * 8 + kc + 1], accO[ct], 0, 0, 0);
        }
      }
#pragma unroll
      for (int ct = 0; ct < 4; ++ct) {
        f32x4 y = accE[ct] + accO[ct];
#pragma unroll
        for (int r = 0; r < 4; ++r)
          xps[tt * 16 + g * 4 + r][h0 + ct * 16 + lr] = y[r] + bias[ct];
      }
    }
    __syncthreads();                                  // xps ready; x-loads drain once/chunk

    // ---- phase 2: 64 recurrence steps, LDS only ----
#pragma unroll 1
    for (int s = 0; s < CHUNK; ++s) {
      float xp[4];
#pragma unroll
      for (int ct = 0; ct < 4; ++ct) xp[ct] = xps[s][h0 + ct * 16 + lr];

      f32x4 accE[4] = {}, accO[4] = {};
      const f16x8* hp = (const f16x8*)hb[cur];
#pragma unroll
      for (int kc = 0; kc < 8; kc += 2) {
        f16x8 hv0 = hp[kc * 4 + g];                   // addr depends only on g: broadcast
        f16x8 hv1 = hp[(kc + 1) * 4 + g];
#pragma unroll
        for (int ct = 0; ct < 4; ++ct) {
          accE[ct] = __builtin_amdgcn_mfma_f32_16x16x32_f16(hv0, whF[ct * 8 + kc],     accE[ct], 0, 0, 0);
          accO[ct] = __builtin_amdgcn_mfma_f32_16x16x32_f16(hv1, whF[ct * 8 + kc + 1], accO[ct], 0, 0, 0);
        }
      }
      _Float16* hn = hb[cur ^ 1];
#pragma unroll
      for (int ct = 0; ct < 4; ++ct) {
        float y = accE[ct][0] + accO[ct][0] + xp[ct]; // every D row = y; reg 0 suffices
        float e = __expf(2.f * y);
        float hv = 1.f - 2.f * __builtin_amdgcn_rcpf(1.f + e);  // tanh
        if (l < 16) {
          outs[s][h0 + ct * 16 + lr] = hv;
          hn[h0 + ct * 16 + lr] = (_Float16)hv;
        }
      }
      __syncthreads();                                // LDS-only drain (fast)
      cur ^= 1;
    }

    // ---- phase 3: bulk flush outs -> global ----
    {
      const f32x4* src = (const f32x4*)outs;
      f32x4* dst = (f32x4*)(io + base + (size_t)t0 * H_);
#pragma unroll
      for (int i = 0; i < (CHUNK * H_ / 4) / 256; ++i)
        dst[i * 256 + tid] = src[i * 256 + tid];
    }
    __syncthreads();                                  // outs free before next chunk
  }
}

extern "C" void kernel_launch(void* const* d_in, const int* in_sizes, int n_in,
                              void* d_out, int out_size, void* d_ws, size_t ws_size,
                              hipStream_t stream) {
  const float* x  = (const float*)d_in[0];
  const float* wx = (const float*)d_in[1];
  const float* wh = (const float*)d_in[2];
  const float* b  = (const float*)d_in[3];
  float* out = (float*)d_out;
  (void)d_ws; (void)ws_size;
  rnn_fused<<<B_, 256, 0, stream>>>(x, wx, wh, b, out);
}